// Round 1
// baseline (2934.177 us; speedup 1.0000x reference)
//
#include <hip/hip_runtime.h>
#include <math.h>

// ---------------- Kernel A: reciprocal row norms ----------------
__global__ void rownorm_kernel(const float* __restrict__ x,
                               float* __restrict__ rnorm, int C) {
    int row = blockIdx.x;
    const float4* xr = (const float4*)(x + (size_t)row * C);
    int n4 = C >> 2;
    float s = 0.f;
    for (int c = threadIdx.x; c < n4; c += blockDim.x) {
        float4 v = xr[c];
        s += v.x * v.x + v.y * v.y + v.z * v.z + v.w * v.w;
    }
    for (int off = 32; off > 0; off >>= 1) s += __shfl_down(s, off, 64);
    __shared__ float red[4];
    int lane = threadIdx.x & 63, wid = threadIdx.x >> 6;
    if (lane == 0) red[wid] = s;
    __syncthreads();
    if (threadIdx.x == 0) {
        float t = red[0] + red[1] + red[2] + red[3];
        float n = fmaxf(sqrtf(t), 1e-6f);
        rnorm[row] = 1.0f / n;
    }
}

// ---------------- Kernel B: cosine = 1 - xn @ xn^T (fp32 vector GEMM) ------
#define BM 128
#define BN 128
#define BK 32

__global__ __launch_bounds__(256) void cosine_gemm(
        const float* __restrict__ x, const float* __restrict__ rnorm,
        float* __restrict__ cosine, int L, int C) {
    __shared__ float As[BK][BM + 4];
    __shared__ float Bs[BK][BN + 4];
    const int tid = threadIdx.x;
    const int i0 = blockIdx.y * BM;
    const int j0 = blockIdx.x * BN;
    const int tr = (tid >> 4) << 3;  // output row offset in tile (0..120)
    const int tc = (tid & 15) << 3;  // output col offset in tile (0..120)
    const int lr = tid >> 3;         // staging row 0..31
    const int lc = (tid & 7) << 2;   // staging col 0,4,...,28
    float acc[8][8] = {};

    for (int k0 = 0; k0 < C; k0 += BK) {
#pragma unroll
        for (int q = 0; q < 4; ++q) {
            int r = lr + q * 32;
            float ra = rnorm[i0 + r];
            float4 va = *(const float4*)(x + (size_t)(i0 + r) * C + k0 + lc);
            As[lc + 0][r] = va.x * ra;
            As[lc + 1][r] = va.y * ra;
            As[lc + 2][r] = va.z * ra;
            As[lc + 3][r] = va.w * ra;
            float rb = rnorm[j0 + r];
            float4 vb = *(const float4*)(x + (size_t)(j0 + r) * C + k0 + lc);
            Bs[lc + 0][r] = vb.x * rb;
            Bs[lc + 1][r] = vb.y * rb;
            Bs[lc + 2][r] = vb.z * rb;
            Bs[lc + 3][r] = vb.w * rb;
        }
        __syncthreads();
#pragma unroll
        for (int kk = 0; kk < BK; ++kk) {
            float a[8], b[8];
#pragma unroll
            for (int m = 0; m < 8; ++m) a[m] = As[kk][tr + m];
#pragma unroll
            for (int n = 0; n < 8; ++n) b[n] = Bs[kk][tc + n];
#pragma unroll
            for (int m = 0; m < 8; ++m)
#pragma unroll
                for (int n = 0; n < 8; ++n)
                    acc[m][n] = fmaf(a[m], b[n], acc[m][n]);
        }
        __syncthreads();
    }
#pragma unroll
    for (int m = 0; m < 8; ++m) {
        float* crow = cosine + (size_t)(i0 + tr + m) * L + j0 + tc;
        float4 o0 = {1.f - acc[m][0], 1.f - acc[m][1], 1.f - acc[m][2], 1.f - acc[m][3]};
        float4 o1 = {1.f - acc[m][4], 1.f - acc[m][5], 1.f - acc[m][6], 1.f - acc[m][7]};
        ((float4*)crow)[0] = o0;
        ((float4*)crow)[1] = o1;
    }
}

// ---------------- Kernel C: second-smallest per row ----------------
__global__ void twosmallest_kernel(const float* __restrict__ cosine,
                                   float* __restrict__ min2, int L) {
    int row = blockIdx.x;
    const float4* r4 = (const float4*)(cosine + (size_t)row * L);
    int n4 = L >> 2;
    float m1 = INFINITY, m2 = INFINITY;
    for (int c = threadIdx.x; c < n4; c += blockDim.x) {
        float4 v = r4[c];
        float vv[4] = {v.x, v.y, v.z, v.w};
#pragma unroll
        for (int t = 0; t < 4; ++t) {
            float u = vv[t];
            if (u < m1) { m2 = m1; m1 = u; }
            else m2 = fminf(m2, u);
        }
    }
    for (int off = 32; off > 0; off >>= 1) {
        float om1 = __shfl_down(m1, off, 64);
        float om2 = __shfl_down(m2, off, 64);
        float nm1 = fminf(m1, om1);
        float nm2 = fminf(fmaxf(m1, om1), fminf(m2, om2));
        m1 = nm1; m2 = nm2;
    }
    __shared__ float s1[4], s2[4];
    int lane = threadIdx.x & 63, wid = threadIdx.x >> 6;
    if (lane == 0) { s1[wid] = m1; s2[wid] = m2; }
    __syncthreads();
    if (threadIdx.x == 0) {
        float a1 = s1[0], a2 = s2[0];
        for (int w = 1; w < 4; ++w) {
            float b1 = s1[w], b2 = s2[w];
            float n2 = fminf(fmaxf(a1, b1), fminf(a2, b2));
            a1 = fminf(a1, b1);
            a2 = n2;
        }
        min2[row] = a2;
    }
}

// ---------------- Kernel D: persistent greedy k-center ----------------
// 1 block x 1024 threads. Thread t owns score indices [4t, 4t+4).
__global__ __launch_bounds__(1024) void greedy_kernel(
        const float* __restrict__ cosine, const float* __restrict__ min2,
        float* __restrict__ sel_out, int L, int k) {
    const int tid = threadIdx.x;
    const int lane = tid & 63, wid = tid >> 6;  // 16 waves
    __shared__ float rv[16];
    __shared__ int rj[16];
    __shared__ int bidx;
    __shared__ int wsum[16];
    __shared__ int woff[16];

    float sc[4];

    // ---- first = argmax(min2), tie -> smallest index ----
    {
        float4 v = ((const float4*)min2)[tid];
        float bv = v.x; int bj = 4 * tid;
        if (v.y > bv) { bv = v.y; bj = 4 * tid + 1; }
        if (v.z > bv) { bv = v.z; bj = 4 * tid + 2; }
        if (v.w > bv) { bv = v.w; bj = 4 * tid + 3; }
#pragma unroll
        for (int off = 32; off > 0; off >>= 1) {
            float ov = __shfl_xor(bv, off, 64);
            int oj = __shfl_xor(bj, off, 64);
            if (ov > bv || (ov == bv && oj < bj)) { bv = ov; bj = oj; }
        }
        if (lane == 0) { rv[wid] = bv; rj[wid] = bj; }
        __syncthreads();
        if (tid == 0) {
            float v0 = rv[0]; int j0 = rj[0];
            for (int w = 1; w < 16; ++w)
                if (rv[w] > v0 || (rv[w] == v0 && rj[w] < j0)) { v0 = rv[w]; j0 = rj[w]; }
            bidx = j0;
        }
        __syncthreads();
    }
    int first = bidx;

    // ---- scores = cosine[first]; scores[first] = -inf ----
    {
        float4 v = ((const float4*)(cosine + (size_t)first * L))[tid];
        sc[0] = v.x; sc[1] = v.y; sc[2] = v.z; sc[3] = v.w;
        if ((first >> 2) == tid) sc[first & 3] = -INFINITY;
    }

    // ---- k-1 greedy steps ----
    for (int it = 0; it < k - 1; ++it) {
        float bv = sc[0]; int bj = 4 * tid;
        if (sc[1] > bv) { bv = sc[1]; bj = 4 * tid + 1; }
        if (sc[2] > bv) { bv = sc[2]; bj = 4 * tid + 2; }
        if (sc[3] > bv) { bv = sc[3]; bj = 4 * tid + 3; }
#pragma unroll
        for (int off = 32; off > 0; off >>= 1) {
            float ov = __shfl_xor(bv, off, 64);
            int oj = __shfl_xor(bj, off, 64);
            if (ov > bv || (ov == bv && oj < bj)) { bv = ov; bj = oj; }
        }
        if (lane == 0) { rv[wid] = bv; rj[wid] = bj; }
        __syncthreads();
        if (tid == 0) {
            float v0 = rv[0]; int j0 = rj[0];
            for (int w = 1; w < 16; ++w)
                if (rv[w] > v0 || (rv[w] == v0 && rj[w] < j0)) { v0 = rv[w]; j0 = rj[w]; }
            bidx = j0;
        }
        __syncthreads();
        int idx = bidx;
        float4 v = ((const float4*)(cosine + (size_t)idx * L))[tid];
        sc[0] = fminf(sc[0], v.x);
        sc[1] = fminf(sc[1], v.y);
        sc[2] = fminf(sc[2], v.z);
        sc[3] = fminf(sc[3], v.w);
        if ((idx >> 2) == tid) sc[idx & 3] = -INFINITY;
    }

    // ---- compact selected (score == -inf) in ascending index order ----
    int f0 = (sc[0] == -INFINITY) ? 1 : 0;
    int f1 = (sc[1] == -INFINITY) ? 1 : 0;
    int f2 = (sc[2] == -INFINITY) ? 1 : 0;
    int f3 = (sc[3] == -INFINITY) ? 1 : 0;
    int cnt = f0 + f1 + f2 + f3;
    int incl = cnt;
#pragma unroll
    for (int off = 1; off < 64; off <<= 1) {
        int n = __shfl_up(incl, off, 64);
        if (lane >= off) incl += n;
    }
    if (lane == 63) wsum[wid] = incl;
    __syncthreads();
    if (tid == 0) {
        int s = 0;
        for (int w = 0; w < 16; ++w) { woff[w] = s; s += wsum[w]; }
    }
    __syncthreads();
    int pos = woff[wid] + incl - cnt;
    if (f0) sel_out[pos++] = (float)(4 * tid + 0);
    if (f1) sel_out[pos++] = (float)(4 * tid + 1);
    if (f2) sel_out[pos++] = (float)(4 * tid + 2);
    if (f3) sel_out[pos++] = (float)(4 * tid + 3);
}

// ---------------- launch ----------------
extern "C" void kernel_launch(void* const* d_in, const int* in_sizes, int n_in,
                              void* d_out, int out_size, void* d_ws, size_t ws_size,
                              hipStream_t stream) {
    const float* x = (const float*)d_in[0];

    // out_size = k + L*L with 1 <= k <= L  =>  L = floor(sqrt(out_size))
    long long L = (long long)floor(sqrt((double)out_size));
    while (L * L > (long long)out_size) --L;
    while ((L + 1) * (L + 1) <= (long long)out_size) ++L;
    long long k = (long long)out_size - L * L;
    long long C = (long long)in_sizes[0] / L;

    float* sel = (float*)d_out;
    float* cosine = (float*)d_out + k;
    float* rnorm = (float*)d_ws;
    float* min2 = rnorm + L;

    rownorm_kernel<<<(int)L, 256, 0, stream>>>(x, rnorm, (int)C);
    dim3 g2((int)(L / BN), (int)(L / BM));
    cosine_gemm<<<g2, 256, 0, stream>>>(x, rnorm, cosine, (int)L, (int)C);
    twosmallest_kernel<<<(int)L, 256, 0, stream>>>(cosine, min2, (int)L);
    greedy_kernel<<<1, 1024, 0, stream>>>(cosine, min2, sel, (int)L, (int)k);
}

// Round 2
// 1993.593 us; speedup vs baseline: 1.4718x; 1.4718x over previous
//
#include <hip/hip_runtime.h>
#include <math.h>

// ---------------- Kernel A: reciprocal row norms ----------------
__global__ void rownorm_kernel(const float* __restrict__ x,
                               float* __restrict__ rnorm, int C) {
    int row = blockIdx.x;
    const float4* xr = (const float4*)(x + (size_t)row * C);
    int n4 = C >> 2;
    float s = 0.f;
    for (int c = threadIdx.x; c < n4; c += blockDim.x) {
        float4 v = xr[c];
        s += v.x * v.x + v.y * v.y + v.z * v.z + v.w * v.w;
    }
    for (int off = 32; off > 0; off >>= 1) s += __shfl_down(s, off, 64);
    __shared__ float red[4];
    int lane = threadIdx.x & 63, wid = threadIdx.x >> 6;
    if (lane == 0) red[wid] = s;
    __syncthreads();
    if (threadIdx.x == 0) {
        float t = red[0] + red[1] + red[2] + red[3];
        float n = fmaxf(sqrtf(t), 1e-6f);
        rnorm[row] = 1.0f / n;
    }
}

// ---------------- Kernel B: cosine = 1 - xn @ xn^T (fp32 vector GEMM) ------
#define BM 128
#define BN 128
#define BK 32

__global__ __launch_bounds__(256) void cosine_gemm(
        const float* __restrict__ x, const float* __restrict__ rnorm,
        float* __restrict__ cosine, int L, int C) {
    __shared__ float As[BK][BM + 4];
    __shared__ float Bs[BK][BN + 4];
    const int tid = threadIdx.x;
    const int i0 = blockIdx.y * BM;
    const int j0 = blockIdx.x * BN;
    const int tr = (tid >> 4) << 3;  // output row offset in tile (0..120)
    const int tc = (tid & 15) << 3;  // output col offset in tile (0..120)
    const int lr = tid >> 3;         // staging row 0..31
    const int lc = (tid & 7) << 2;   // staging col 0,4,...,28
    float acc[8][8] = {};

    for (int k0 = 0; k0 < C; k0 += BK) {
#pragma unroll
        for (int q = 0; q < 4; ++q) {
            int r = lr + q * 32;
            float ra = rnorm[i0 + r];
            float4 va = *(const float4*)(x + (size_t)(i0 + r) * C + k0 + lc);
            As[lc + 0][r] = va.x * ra;
            As[lc + 1][r] = va.y * ra;
            As[lc + 2][r] = va.z * ra;
            As[lc + 3][r] = va.w * ra;
            float rb = rnorm[j0 + r];
            float4 vb = *(const float4*)(x + (size_t)(j0 + r) * C + k0 + lc);
            Bs[lc + 0][r] = vb.x * rb;
            Bs[lc + 1][r] = vb.y * rb;
            Bs[lc + 2][r] = vb.z * rb;
            Bs[lc + 3][r] = vb.w * rb;
        }
        __syncthreads();
#pragma unroll
        for (int kk = 0; kk < BK; ++kk) {
            float a[8], b[8];
#pragma unroll
            for (int m = 0; m < 8; ++m) a[m] = As[kk][tr + m];
#pragma unroll
            for (int n = 0; n < 8; ++n) b[n] = Bs[kk][tc + n];
#pragma unroll
            for (int m = 0; m < 8; ++m)
#pragma unroll
                for (int n = 0; n < 8; ++n)
                    acc[m][n] = fmaf(a[m], b[n], acc[m][n]);
        }
        __syncthreads();
    }
#pragma unroll
    for (int m = 0; m < 8; ++m) {
        float* crow = cosine + (size_t)(i0 + tr + m) * L + j0 + tc;
        float4 o0 = {1.f - acc[m][0], 1.f - acc[m][1], 1.f - acc[m][2], 1.f - acc[m][3]};
        float4 o1 = {1.f - acc[m][4], 1.f - acc[m][5], 1.f - acc[m][6], 1.f - acc[m][7]};
        ((float4*)crow)[0] = o0;
        ((float4*)crow)[1] = o1;
    }
}

// ---------------- Kernel C: second-smallest per row ----------------
__global__ void twosmallest_kernel(const float* __restrict__ cosine,
                                   float* __restrict__ min2, int L) {
    int row = blockIdx.x;
    const float4* r4 = (const float4*)(cosine + (size_t)row * L);
    int n4 = L >> 2;
    float m1 = INFINITY, m2 = INFINITY;
    for (int c = threadIdx.x; c < n4; c += blockDim.x) {
        float4 v = r4[c];
        float vv[4] = {v.x, v.y, v.z, v.w};
#pragma unroll
        for (int t = 0; t < 4; ++t) {
            float u = vv[t];
            if (u < m1) { m2 = m1; m1 = u; }
            else m2 = fminf(m2, u);
        }
    }
    for (int off = 32; off > 0; off >>= 1) {
        float om1 = __shfl_down(m1, off, 64);
        float om2 = __shfl_down(m2, off, 64);
        float nm1 = fminf(m1, om1);
        float nm2 = fminf(fmaxf(m1, om1), fminf(m2, om2));
        m1 = nm1; m2 = nm2;
    }
    __shared__ float s1[4], s2[4];
    int lane = threadIdx.x & 63, wid = threadIdx.x >> 6;
    if (lane == 0) { s1[wid] = m1; s2[wid] = m2; }
    __syncthreads();
    if (threadIdx.x == 0) {
        float a1 = s1[0], a2 = s2[0];
        for (int w = 1; w < 4; ++w) {
            float b1 = s1[w], b2 = s2[w];
            float n2 = fminf(fmaxf(a1, b1), fminf(a2, b2));
            a1 = fminf(a1, b1);
            a2 = n2;
        }
        min2[row] = a2;
    }
}

// ---------------- Kernel D: persistent greedy k-center ----------------
// 1 block x 256 threads (4 waves, 1/SIMD). Thread t owns scores [16t, 16t+16).
// One barrier per step: parity double-buffered reduce slots kill the WAR
// hazard; all 256 threads redundantly combine the 4 per-wave results
// (no serial tid0 phase, no second barrier).
__global__ __launch_bounds__(256) void greedy_kernel(
        const float* __restrict__ cosine, const float* __restrict__ min2,
        float* __restrict__ sel_out, int L, int k) {
    const int tid = threadIdx.x;
    const int lane = tid & 63, wid = tid >> 6;  // 4 waves
    __shared__ float rv[2][4];
    __shared__ int rj[2][4];
    __shared__ int wsum[4];

    const int base = tid << 4;
    float sc[16];

    // ---- block argmax: local (bv,bj) -> selected global index ----
    auto block_argmax = [&](float bv, int bj, int p) -> int {
#pragma unroll
        for (int off = 32; off > 0; off >>= 1) {
            float ov = __shfl_xor(bv, off, 64);
            int oj = __shfl_xor(bj, off, 64);
            if (ov > bv || (ov == bv && oj < bj)) { bv = ov; bj = oj; }
        }
        if (lane == 0) { rv[p][wid] = bv; rj[p][wid] = bj; }
        __syncthreads();
        float v0 = rv[p][0]; int j0 = rj[p][0];
#pragma unroll
        for (int w = 1; w < 4; ++w) {
            float vw = rv[p][w]; int jw = rj[p][w];
            if (vw > v0 || (vw == v0 && jw < j0)) { v0 = vw; j0 = jw; }
        }
        return j0;
    };

    // ---- first = argmax(min2) ----
    float bv = -INFINITY; int bj = base;
    {
        const float4* m4 = (const float4*)min2;
#pragma unroll
        for (int q = 0; q < 4; ++q) {
            float4 v = m4[tid * 4 + q];
            float vv[4] = {v.x, v.y, v.z, v.w};
#pragma unroll
            for (int t = 0; t < 4; ++t) {
                if (vv[t] > bv) { bv = vv[t]; bj = base + 4 * q + t; }
            }
        }
    }
    int first = block_argmax(bv, bj, 0);

    // ---- scores = cosine[first]; scores[first] = -inf; local argmax ----
    {
        const float4* row4 = (const float4*)(cosine + (size_t)first * L);
#pragma unroll
        for (int q = 0; q < 4; ++q) {
            float4 v = row4[tid * 4 + q];
            sc[4 * q + 0] = v.x; sc[4 * q + 1] = v.y;
            sc[4 * q + 2] = v.z; sc[4 * q + 3] = v.w;
        }
        if ((first >> 4) == tid) sc[first & 15] = -INFINITY;
        bv = -INFINITY; bj = base;
#pragma unroll
        for (int j = 0; j < 16; ++j)
            if (sc[j] > bv) { bv = sc[j]; bj = base + j; }
    }

    // ---- k-1 greedy steps, one barrier each ----
    int p = 1;
    for (int it = 0; it < k - 1; ++it) {
        int idx = block_argmax(bv, bj, p);
        p ^= 1;
        const float4* row4 = (const float4*)(cosine + (size_t)idx * L);
        float4 r0 = row4[tid * 4 + 0];
        float4 r1 = row4[tid * 4 + 1];
        float4 r2 = row4[tid * 4 + 2];
        float4 r3 = row4[tid * 4 + 3];
        float rr[16] = {r0.x, r0.y, r0.z, r0.w, r1.x, r1.y, r1.z, r1.w,
                        r2.x, r2.y, r2.z, r2.w, r3.x, r3.y, r3.z, r3.w};
#pragma unroll
        for (int j = 0; j < 16; ++j) sc[j] = fminf(sc[j], rr[j]);
        if ((idx >> 4) == tid) sc[idx & 15] = -INFINITY;
        bv = -INFINITY; bj = base;
#pragma unroll
        for (int j = 0; j < 16; ++j)
            if (sc[j] > bv) { bv = sc[j]; bj = base + j; }  // strict > keeps first-max tie
    }

    // ---- compact selected (score == -inf) in ascending index order ----
    unsigned flags = 0; int cnt = 0;
#pragma unroll
    for (int j = 0; j < 16; ++j)
        if (sc[j] == -INFINITY) { flags |= 1u << j; ++cnt; }
    int incl = cnt;
#pragma unroll
    for (int off = 1; off < 64; off <<= 1) {
        int n = __shfl_up(incl, off, 64);
        if (lane >= off) incl += n;
    }
    if (lane == 63) wsum[wid] = incl;
    __syncthreads();
    int off0 = 0;
#pragma unroll
    for (int w = 0; w < 4; ++w)
        if (w < wid) off0 += wsum[w];
    int pos = off0 + incl - cnt;
#pragma unroll
    for (int j = 0; j < 16; ++j)
        if ((flags >> j) & 1) sel_out[pos++] = (float)(base + j);
}

// ---------------- launch ----------------
extern "C" void kernel_launch(void* const* d_in, const int* in_sizes, int n_in,
                              void* d_out, int out_size, void* d_ws, size_t ws_size,
                              hipStream_t stream) {
    const float* x = (const float*)d_in[0];

    // out_size = k + L*L with 1 <= k <= L  =>  L = floor(sqrt(out_size))
    long long L = (long long)floor(sqrt((double)out_size));
    while (L * L > (long long)out_size) --L;
    while ((L + 1) * (L + 1) <= (long long)out_size) ++L;
    long long k = (long long)out_size - L * L;
    long long C = (long long)in_sizes[0] / L;

    float* sel = (float*)d_out;
    float* cosine = (float*)d_out + k;
    float* rnorm = (float*)d_ws;
    float* min2 = rnorm + L;

    rownorm_kernel<<<(int)L, 256, 0, stream>>>(x, rnorm, (int)C);
    dim3 g2((int)(L / BN), (int)(L / BM));
    cosine_gemm<<<g2, 256, 0, stream>>>(x, rnorm, cosine, (int)L, (int)C);
    twosmallest_kernel<<<(int)L, 256, 0, stream>>>(cosine, min2, (int)L);
    greedy_kernel<<<1, 256, 0, stream>>>(cosine, min2, sel, (int)L, (int)k);
}